// Round 1
// 4790.103 us; speedup vs baseline: 1.2783x; 1.2783x over previous
//
#include <hip/hip_runtime.h>
#include <hip/hip_bf16.h>

#define SEQ   256
#define BATCH 256
#define KDIM  1024
#define ODIM  1024

typedef __bf16 bf16_t;
typedef bf16_t bf16x8 __attribute__((ext_vector_type(8)));
typedef float  f32x4  __attribute__((ext_vector_type(4)));
typedef float  f32x2  __attribute__((ext_vector_type(2)));

__device__ __forceinline__ bf16x8 cvt8(float4 a, float4 b) {
    return (bf16x8){(bf16_t)a.x, (bf16_t)a.y, (bf16_t)a.z, (bf16_t)a.w,
                    (bf16_t)b.x, (bf16_t)b.y, (bf16_t)b.z, (bf16_t)b.w};
}

#define MFMA16 __builtin_amdgcn_mfma_f32_16x16x32_bf16

// Per-m-group barrier: 32 blocks, monotonic counter, agent-scope release/acquire
// (correct regardless of workgroup->XCD placement; cooperative launch guarantees
// co-residency so the spin cannot deadlock).
__device__ __forceinline__ void group_barrier(unsigned* ctr, unsigned target) {
    __syncthreads();
    if (threadIdx.x == 0) {
        __hip_atomic_fetch_add(ctr, 1u, __ATOMIC_RELEASE, __HIP_MEMORY_SCOPE_AGENT);
        while (__hip_atomic_load(ctr, __ATOMIC_RELAXED, __HIP_MEMORY_SCOPE_AGENT) < target)
            __builtin_amdgcn_s_sleep(1);
        (void)__hip_atomic_load(ctr, __ATOMIC_ACQUIRE, __HIP_MEMORY_SCOPE_AGENT);
    }
    __syncthreads();
}

// ---------------------------------------------------------------------------
// Persistent GRU: 256 blocks (1/CU) x 512 threads (8 waves), all 256 timesteps.
// Block (mg = blockIdx&7, nt = blockIdx>>3) owns output tile rows mg*32..+32,
// cols nt*32..+32 forever. Wave wv: wnh = wv&1 (n-half), kq = wv>>1 (K-quarter).
// Weights: Wrx,Wrh,Wux,Wuh,Wcx as MFMA fragments in VGPRs (160 regs/wave),
// Wch as pre-gathered fragments in LDS (64 KB). K-partials reduced via LDS.
// h_old for the gate equation never leaves registers (tile is self-owned).
// ---------------------------------------------------------------------------
template<bool XB16>
__global__ __launch_bounds__(512, 2) void gru_persistent(
    const float* __restrict__ x, bf16_t* __restrict__ xb,
    const float* __restrict__ h0,
    float* __restrict__ hseq, float* __restrict__ hlast,
    bf16_t* __restrict__ hb, unsigned* __restrict__ bar,
    const float* __restrict__ Wrx, const float* __restrict__ Wrh,
    const float* __restrict__ Wux, const float* __restrict__ Wuh,
    const float* __restrict__ Wcx, const float* __restrict__ Wch,
    const float* __restrict__ brx, const float* __restrict__ brh,
    const float* __restrict__ bux, const float* __restrict__ buh,
    const float* __restrict__ bcx, const float* __restrict__ bch)
{
    __shared__ bf16x8 sWch[4096];   // [wnh][kq][ks][quad][lr] fragment-major, 64 KB
    __shared__ f32x2  sRed[8192];   // [wnh][kq][slot16][lane64], 64 KB

    const int tid    = threadIdx.x;
    const int mg     = blockIdx.x & 7;    // m-group: XCD-affine under %8 round-robin
    const int nt     = blockIdx.x >> 3;   // 0..31 n-tile
    const int m_base = mg * 32;
    const int n_base = nt * 32;
    const int lane   = tid & 63;
    const int wv     = tid >> 6;
    const int wnh    = wv & 1;            // n-half (cols wnh*16..+16)
    const int kq     = wv >> 1;           // K-quarter (k in [kq*256, kq*256+256))
    const int lr     = lane & 15;
    const int quad   = lane >> 4;
    const int wm     = kq >> 1;           // epilogue: which m-half this wave finishes
    const int rp     = kq & 1;            // epilogue: which r-pair (rows rp*2, rp*2+1)

    unsigned* ctr = bar + mg * 64;        // 256-B spaced counters

    // ---- preamble 1: x fp32 -> bf16, group-local slab (rows m_base..+32, all t) ----
    if constexpr (XB16) {
        for (int tt = 0; tt < 8; ++tt) {
            const size_t base = ((size_t)(nt * 8 + tt) * BATCH + m_base) * KDIM;
            #pragma unroll
            for (int f = 0; f < 8; ++f) {
                const size_t e = base + (size_t)(f * 512 + tid) * 8;
                float4 a = *(const float4*)&x[e];
                float4 b = *(const float4*)&x[e + 4];
                *(bf16x8*)&xb[e] = cvt8(a, b);
            }
        }
    }

    // ---- preamble 2: h0 -> hb[0] (own 32x32 tile) ----
    {
        const int r = tid >> 4;
        const int c = (tid & 15) * 2;
        const size_t i0 = (size_t)(m_base + r) * ODIM + n_base + c;
        hb[i0]     = (bf16_t)h0[i0];
        hb[i0 + 1] = (bf16_t)h0[i0 + 1];
    }

    // ---- preamble 3: 5 weight matrices -> registers as MFMA B-fragments ----
    // fragment (mat, ks): lane(quad,lr) holds W[n_base+wnh*16+lr][kq*256+ks*32+quad*8 ..+8]
    bf16x8 wreg[5][8];
    {
        const size_t wrow = (size_t)(n_base + wnh * 16 + lr) * KDIM + kq * 256 + quad * 8;
        #define LOADW(wi, SRC) { \
            const float* s_ = SRC + wrow; \
            _Pragma("unroll") \
            for (int ks = 0; ks < 8; ++ks) { \
                float4 a_ = *(const float4*)(s_ + ks * 32); \
                float4 b_ = *(const float4*)(s_ + ks * 32 + 4); \
                wreg[wi][ks] = cvt8(a_, b_); \
            } }
        LOADW(0, Wrx) LOADW(1, Wrh) LOADW(2, Wux) LOADW(3, Wuh) LOADW(4, Wcx)
        #undef LOADW
    }

    // ---- preamble 4: Wch -> LDS, fragment-major (lane-linear reads, conflict-free) ----
    #pragma unroll
    for (int j = 0; j < 8; ++j) {
        const int f    = tid + 512 * j;
        const int flr  = f & 15;
        const int fq   = (f >> 4) & 3;
        const int fks  = (f >> 6) & 7;
        const int fkq  = (f >> 9) & 3;
        const int fwnh = (f >> 11) & 1;
        const float* s_ = Wch + (size_t)(n_base + fwnh * 16 + flr) * KDIM
                              + fkq * 256 + fks * 32 + fq * 8;
        float4 a = *(const float4*)s_;
        float4 b = *(const float4*)(s_ + 4);
        sWch[f] = cvt8(a, b);
    }

    // ---- per-lane constants + register-resident h_old ----
    const int o   = n_base + wnh * 16 + lr;                  // output column
    const int ob0 = m_base + wm * 16 + quad * 4 + rp * 2;    // first of 2 output rows
    const float vbrx = brx[o], vbrh = brh[o];
    const float vbux = bux[o], vbuh = buh[o];
    const float vbcx = bcx[o], vbch = bch[o];
    float hk0 = h0[(size_t)ob0 * ODIM + o];
    float hk1 = h0[(size_t)(ob0 + 1) * ODIM + o];

    const int wch_base  = (wnh * 4 + kq) * 512 + quad * 16 + lr;
    const int red_wb    = (wnh * 4 + kq) * 1024 + lane;
    const size_t a_off0 = (size_t)(m_base + lr) * KDIM + kq * 256 + quad * 8;

    group_barrier(ctr, 32u);   // xb/hb visible to the whole m-group

    for (int t = 0; t < SEQ; ++t) {
        const bf16_t* __restrict__ hsrc = hb + (size_t)(t & 1) * ((size_t)BATCH * ODIM);
        bf16_t* __restrict__ hdst       = hb + (size_t)((t + 1) & 1) * ((size_t)BATCH * ODIM);

        f32x4 acc[4][2];   // gate-sets: 0=r(Wrx,Wrh) 1=z(Wux,Wuh) 2=cx 3=ch; [m-half]
        #pragma unroll
        for (int g = 0; g < 4; ++g) {
            acc[g][0] = (f32x4){0.f, 0.f, 0.f, 0.f};
            acc[g][1] = (f32x4){0.f, 0.f, 0.f, 0.f};
        }

        const bf16_t* __restrict__ hp0 = hsrc + a_off0;
        const bf16_t* __restrict__ hp1 = hp0 + 16 * KDIM;

        #define MFMA12(ks) do { \
            const bf16x8 ah0 = *(const bf16x8*)(hp0 + (ks) * 32); \
            const bf16x8 ah1 = *(const bf16x8*)(hp1 + (ks) * 32); \
            const bf16x8 wch = sWch[wch_base + (ks) * 64]; \
            acc[0][0] = MFMA16(ax0, wreg[0][ks], acc[0][0], 0, 0, 0); \
            acc[0][1] = MFMA16(ax1, wreg[0][ks], acc[0][1], 0, 0, 0); \
            acc[0][0] = MFMA16(ah0, wreg[1][ks], acc[0][0], 0, 0, 0); \
            acc[0][1] = MFMA16(ah1, wreg[1][ks], acc[0][1], 0, 0, 0); \
            acc[1][0] = MFMA16(ax0, wreg[2][ks], acc[1][0], 0, 0, 0); \
            acc[1][1] = MFMA16(ax1, wreg[2][ks], acc[1][1], 0, 0, 0); \
            acc[1][0] = MFMA16(ah0, wreg[3][ks], acc[1][0], 0, 0, 0); \
            acc[1][1] = MFMA16(ah1, wreg[3][ks], acc[1][1], 0, 0, 0); \
            acc[2][0] = MFMA16(ax0, wreg[4][ks], acc[2][0], 0, 0, 0); \
            acc[2][1] = MFMA16(ax1, wreg[4][ks], acc[2][1], 0, 0, 0); \
            acc[3][0] = MFMA16(ah0, wch, acc[3][0], 0, 0, 0); \
            acc[3][1] = MFMA16(ah1, wch, acc[3][1], 0, 0, 0); \
        } while (0)

        if constexpr (XB16) {
            const bf16_t* __restrict__ xp0 = xb + (size_t)t * BATCH * KDIM + a_off0;
            const bf16_t* __restrict__ xp1 = xp0 + 16 * KDIM;
            #pragma unroll
            for (int ks = 0; ks < 8; ++ks) {
                const bf16x8 ax0 = *(const bf16x8*)(xp0 + ks * 32);
                const bf16x8 ax1 = *(const bf16x8*)(xp1 + ks * 32);
                MFMA12(ks);
            }
        } else {
            const float* __restrict__ xf0 = x + (size_t)t * BATCH * KDIM + a_off0;
            const float* __restrict__ xf1 = xf0 + 16 * KDIM;
            #pragma unroll
            for (int ks = 0; ks < 8; ++ks) {
                float4 a0 = *(const float4*)(xf0 + ks * 32);
                float4 b0 = *(const float4*)(xf0 + ks * 32 + 4);
                float4 a1 = *(const float4*)(xf1 + ks * 32);
                float4 b1 = *(const float4*)(xf1 + ks * 32 + 4);
                const bf16x8 ax0 = cvt8(a0, b0);
                const bf16x8 ax1 = cvt8(a1, b1);
                MFMA12(ks);
            }
        }
        #undef MFMA12

        // ---- cross-kq reduction: split each f32x4 into r-pairs so readers index
        // statically (no dynamic vector extract -> no scratch) ----
        #pragma unroll
        for (int g = 0; g < 4; ++g) {
            #pragma unroll
            for (int w2 = 0; w2 < 2; ++w2) {
                const int s0 = red_wb + ((g * 2 + w2) * 2) * 64;
                sRed[s0]      = (f32x2){acc[g][w2][0], acc[g][w2][1]};
                sRed[s0 + 64] = (f32x2){acc[g][w2][2], acc[g][w2][3]};
            }
        }
        __syncthreads();

        float s0v[4], s1v[4];
        #pragma unroll
        for (int g = 0; g < 4; ++g) {
            const int slot = ((g * 2 + wm) * 2 + rp) * 64 + lane;
            f32x2 v = sRed[wnh * 4096 + slot]
                    + sRed[wnh * 4096 + 1024 + slot]
                    + sRed[wnh * 4096 + 2048 + slot]
                    + sRed[wnh * 4096 + 3072 + slot];
            s0v[g] = v[0];
            s1v[g] = v[1];
        }

        // ---- gates for this wave's 2 output elements (h_old from registers) ----
        float* __restrict__ hs = hseq + (size_t)t * ((size_t)BATCH * ODIM);
        const size_t i0 = (size_t)ob0 * ODIM + o;
        const size_t i1 = i0 + ODIM;
        {
            const float pre_r = s0v[0] + vbrx + vbrh;
            const float rg    = 1.f / (1.f + __expf(-pre_r));
            const float pre_z = s0v[1] + vbux + vbuh;
            const float zg    = 1.f / (1.f + __expf(-pre_z));
            const float pre_n = s0v[2] + vbcx + rg * (s0v[3] + vbch);
            const float ng    = tanhf(pre_n);
            hk0 = (1.f - zg) * ng + zg * hk0;
            __builtin_nontemporal_store(hk0, &hs[i0]);
            hdst[i0] = (bf16_t)hk0;
        }
        {
            const float pre_r = s1v[0] + vbrx + vbrh;
            const float rg    = 1.f / (1.f + __expf(-pre_r));
            const float pre_z = s1v[1] + vbux + vbuh;
            const float zg    = 1.f / (1.f + __expf(-pre_z));
            const float pre_n = s1v[2] + vbcx + rg * (s1v[3] + vbch);
            const float ng    = tanhf(pre_n);
            hk1 = (1.f - zg) * ng + zg * hk1;
            __builtin_nontemporal_store(hk1, &hs[i1]);
            hdst[i1] = (bf16_t)hk1;
        }
        if (t == SEQ - 1) {
            __builtin_nontemporal_store(hk0, &hlast[i0]);
            __builtin_nontemporal_store(hk1, &hlast[i1]);
        }

        group_barrier(ctr, 32u * (t + 2));
    }
}

// ---------------------------------------------------------------------------
extern "C" void kernel_launch(void* const* d_in, const int* in_sizes, int n_in,
                              void* d_out, int out_size, void* d_ws, size_t ws_size,
                              hipStream_t stream)
{
    (void)in_sizes; (void)n_in; (void)out_size;
    const float* x   = (const float*)d_in[0];
    const float* h0  = (const float*)d_in[1];
    const float* Wrx = (const float*)d_in[2];
    const float* brx = (const float*)d_in[3];
    const float* Wrh = (const float*)d_in[4];
    const float* brh = (const float*)d_in[5];
    const float* Wux = (const float*)d_in[6];
    const float* bux = (const float*)d_in[7];
    const float* Wuh = (const float*)d_in[8];
    const float* buh = (const float*)d_in[9];
    const float* Wcx = (const float*)d_in[10];
    const float* bcx = (const float*)d_in[11];
    const float* Wch = (const float*)d_in[12];
    const float* bch = (const float*)d_in[13];

    float* hseq  = (float*)d_out;
    float* hlast = hseq + (size_t)SEQ * BATCH * ODIM;

    // ws layout: [0,4K) barrier counters | [4K, +1MB) h bf16 ping-pong | x bf16 copy
    unsigned* bar = (unsigned*)d_ws;
    bf16_t* hb = (bf16_t*)((char*)d_ws + 4096);
    bf16_t* xb = (bf16_t*)((char*)d_ws + 4096 + (size_t)2 * BATCH * ODIM * sizeof(bf16_t));
    const size_t need = 4096 + (size_t)2 * BATCH * ODIM * sizeof(bf16_t)
                      + (size_t)SEQ * BATCH * KDIM * sizeof(bf16_t);

    hipMemsetAsync(d_ws, 0, 4096, stream);

    void* args[] = {
        (void*)&x, (void*)&xb, (void*)&h0, (void*)&hseq, (void*)&hlast,
        (void*)&hb, (void*)&bar,
        (void*)&Wrx, (void*)&Wrh, (void*)&Wux, (void*)&Wuh, (void*)&Wcx, (void*)&Wch,
        (void*)&brx, (void*)&brh, (void*)&bux, (void*)&buh, (void*)&bcx, (void*)&bch };

    if (ws_size >= need)
        hipLaunchCooperativeKernel((void*)gru_persistent<true>,
                                   dim3(256), dim3(512), args, 0, stream);
    else
        hipLaunchCooperativeKernel((void*)gru_persistent<false>,
                                   dim3(256), dim3(512), args, 0, stream);
}